// Round 1
// baseline (1581.100 us; speedup 1.0000x reference)
//
#include <hip/hip_runtime.h>

// EdgeFeatGAE: 2-layer GCN (R=4 relations share x, W1, W2), output = sum over
// embed dim -> [R, N].
// Key algebra: layer2 collapses to scalar per node via wrow[j] = sum_k W2[j][k];
// H0 = x@W1 is relation-independent.

constexpr int N    = 100000;
constexpr int E    = 1600000;
constexpr int R    = 4;
constexpr int FEAT = 128;
constexpr int HID  = 32;   // power of 2, t>>5 / t&31 indexing
constexpr int EMB  = 16;

// ---------------- H0 = x @ W1  [N,32] ----------------
__global__ void k_gemm_h0(const float* __restrict__ x, const float* __restrict__ W1,
                          float* __restrict__ H0) {
    int t = blockIdx.x * blockDim.x + threadIdx.x;
    if (t >= N * HID) return;
    int j = t & (HID - 1);
    int i = t >> 5;
    const float* xr = x + (size_t)i * FEAT;
    float acc = 0.f;
#pragma unroll 8
    for (int k = 0; k < FEAT; ++k)
        acc = fmaf(xr[k], W1[k * HID + j], acc);   // xr[k] broadcast across 32 lanes
    H0[t] = acc;
}

// ---------------- deg = 1 (self loop) ----------------
__global__ void k_fill1(float* __restrict__ p, int n) {
    int t = blockIdx.x * blockDim.x + threadIdx.x;
    if (t < n) p[t] = 1.0f;
}

// ---------------- deg count: one thread per (r, edge) ----------------
__global__ void k_count(const int* __restrict__ eis, float* __restrict__ deg, int nr) {
    int t = blockIdx.x * blockDim.x + threadIdx.x;
    if (t >= nr * E) return;
    int r = t / E;
    int e = t - r * E;
    int dst = eis[r * 2 * E + E + e];
    atomicAdd(&deg[r * N + dst], 1.0f);
}

// ---------------- dinv = rsqrt(deg) in place (deg >= 1 always) ----------------
__global__ void k_dinv(float* __restrict__ d, int n) {
    int t = blockIdx.x * blockDim.x + threadIdx.x;
    if (t < n) d[t] = rsqrtf(d[t]);
}

// ---------------- acc[r][i][j] = dinv[r][i] * H0[i][j]  (self-loop term) ----------------
__global__ void k_accinit(const float* __restrict__ dinv, const float* __restrict__ H0,
                          float* __restrict__ acc, int nr) {
    int t = blockIdx.x * blockDim.x + threadIdx.x;
    if (t >= nr * N * HID) return;
    int j = t & 31;
    int ri = t >> 5;
    int i = ri % N;
    acc[t] = dinv[ri] * H0[i * HID + j];
}

// ---------------- layer-1 aggregation: 32 lanes per (r, edge) ----------------
__global__ void k_agg1(const int* __restrict__ eis, const float* __restrict__ dinv,
                       const float* __restrict__ H0, float* __restrict__ acc, int nr) {
    int t = blockIdx.x * blockDim.x + threadIdx.x;   // < nr*E*32 = 204.8M < 2^31
    if (t >= nr * E * HID) return;
    int j = t & 31;
    int re = t >> 5;
    int r = re / E;
    int e = re - r * E;
    int src = eis[r * 2 * E + e];           // broadcast within the 32-lane group
    int dst = eis[r * 2 * E + E + e];
    float v = dinv[r * N + src] * H0[src * HID + j];   // 128 B coalesced gather
    atomicAdd(&acc[((r * N + dst) << 5) + j], v);
}

// ---------------- node pass: h1 = relu(dinv*acc + b1); g = h1 . wrow; out self term ----
__global__ void k_node(const float* __restrict__ dinv, const float* __restrict__ acc,
                       const float* __restrict__ b1, const float* __restrict__ W2,
                       float* __restrict__ g, float* __restrict__ out, int nr) {
    int t = blockIdx.x * blockDim.x + threadIdx.x;
    if (t >= nr * N * HID) return;
    int j = t & 31;
    int ri = t >> 5;
    float di = dinv[ri];
    float h = fmaxf(fmaf(di, acc[t], b1[j]), 0.f);
    float wr = 0.f;
#pragma unroll
    for (int k = 0; k < EMB; ++k) wr += W2[j * EMB + k];   // wrow[j], L1-cached
    float p = h * wr;
#pragma unroll
    for (int off = 16; off > 0; off >>= 1) p += __shfl_xor(p, off, 32);
    if (j == 0) {
        g[ri] = p;
        out[ri] = di * p;   // self-loop term of layer 2 (initializes d_out)
    }
}

// ---------------- layer-2 aggregation: scalar per edge ----------------
__global__ void k_agg2(const int* __restrict__ eis, const float* __restrict__ dinv,
                       const float* __restrict__ g, float* __restrict__ out, int nr) {
    int t = blockIdx.x * blockDim.x + threadIdx.x;
    if (t >= nr * E) return;
    int r = t / E;
    int e = t - r * E;
    int src = eis[r * 2 * E + e];
    int dst = eis[r * 2 * E + E + e];
    atomicAdd(&out[r * N + dst], dinv[r * N + src] * g[r * N + src]);
}

// ---------------- finalize: out = dinv*out + sum(b2) ----------------
__global__ void k_final(const float* __restrict__ dinv, const float* __restrict__ b2,
                        float* __restrict__ out, int n) {
    int t = blockIdx.x * blockDim.x + threadIdx.x;
    if (t >= n) return;
    float sb = 0.f;
#pragma unroll
    for (int k = 0; k < EMB; ++k) sb += b2[k];
    out[t] = fmaf(dinv[t], out[t], sb);
}

extern "C" void kernel_launch(void* const* d_in, const int* in_sizes, int n_in,
                              void* d_out, int out_size, void* d_ws, size_t ws_size,
                              hipStream_t stream) {
    const float* x  = (const float*)d_in[0];
    const int*  eis = (const int*)d_in[1];
    const float* W1 = (const float*)d_in[2];
    const float* b1 = (const float*)d_in[3];
    const float* W2 = (const float*)d_in[4];
    const float* b2 = (const float*)d_in[5];
    float* out = (float*)d_out;
    float* ws  = (float*)d_ws;

    // ws layout: H0 [N*32] | dinv [nrp*N] | acc [nrp*N*32] | g [nrp*N]
    // fused (all 4 relations): 67.2 MB; sequential fallback: 26.4 MB
    size_t fusedFloats = (size_t)N * HID + (size_t)R * N * (HID + 2);
    int nrp = (ws_size >= fusedFloats * sizeof(float)) ? R : 1;

    float* H0   = ws;
    float* dinv = H0 + (size_t)N * HID;
    float* acc  = dinv + (size_t)nrp * N;
    float* g    = acc + (size_t)nrp * N * HID;

    constexpr int BS = 256;
    k_gemm_h0<<<(N * HID + BS - 1) / BS, BS, 0, stream>>>(x, W1, H0);

    for (int r0 = 0; r0 < R; r0 += nrp) {
        const int* eis_r = eis + (size_t)r0 * 2 * E;
        float* out_r = out + (size_t)r0 * N;
        int nN  = nrp * N;
        int nNH = nrp * N * HID;
        long long nE  = (long long)nrp * E;
        long long nEH = (long long)nrp * E * HID;

        k_fill1 <<<(nN + BS - 1) / BS, BS, 0, stream>>>(dinv, nN);
        k_count <<<(int)((nE + BS - 1) / BS), BS, 0, stream>>>(eis_r, dinv, nrp);
        k_dinv  <<<(nN + BS - 1) / BS, BS, 0, stream>>>(dinv, nN);
        k_accinit<<<(nNH + BS - 1) / BS, BS, 0, stream>>>(dinv, H0, acc, nrp);
        k_agg1  <<<(int)((nEH + BS - 1) / BS), BS, 0, stream>>>(eis_r, dinv, H0, acc, nrp);
        k_node  <<<(nNH + BS - 1) / BS, BS, 0, stream>>>(dinv, acc, b1, W2, g, out_r, nrp);
        k_agg2  <<<(int)((nE + BS - 1) / BS), BS, 0, stream>>>(eis_r, dinv, g, out_r, nrp);
        k_final <<<(nN + BS - 1) / BS, BS, 0, stream>>>(dinv, b2, out_r, nN);
    }
}

// Round 2
// 1330.244 us; speedup vs baseline: 1.1886x; 1.1886x over previous
//
#include <hip/hip_runtime.h>

// EdgeFeatGAE: 2-layer GCN (R=4 relations share x, W1, W2), out = sum over
// embed dim -> [R, N].
// Algebra: layer2 collapses to scalar per node (wrow[j] = sum_k W2[j][k]);
// H0 = x@W1 is relation-independent.
// R1 change: CSR (counting-sort by dst) + gather kernels. Eliminates the 205M
// float scatter-atomics of k_agg1 (663us, 800MB HBM write-through) and the
// 51.2MB acc array entirely.

constexpr int N    = 100000;
constexpr int E    = 1600000;
constexpr int R    = 4;
constexpr int FEAT = 128;
constexpr int HID  = 32;
constexpr int EMB  = 16;
constexpr int M    = R * N;        // 400000 nodes total across relations
constexpr int BS   = 256;
constexpr int NB   = (M + BS - 1) / BS;   // scan blocks = 1563

// ---------------- H0 = x @ W1  [N,32] ----------------
__global__ void k_gemm_h0(const float* __restrict__ x, const float* __restrict__ W1,
                          float* __restrict__ H0) {
    int t = blockIdx.x * blockDim.x + threadIdx.x;
    if (t >= N * HID) return;
    int j = t & (HID - 1);
    int i = t >> 5;
    const float* xr = x + (size_t)i * FEAT;
    float acc = 0.f;
#pragma unroll 8
    for (int k = 0; k < FEAT; ++k)
        acc = fmaf(xr[k], W1[k * HID + j], acc);   // xr[k] broadcast across 32 lanes
    H0[t] = acc;
}

// ---------------- histogram of dst (self-loop excluded; added as +1 later) ----
__global__ void k_count(const int* __restrict__ eis, int* __restrict__ cnt) {
    int t = blockIdx.x * blockDim.x + threadIdx.x;
    if (t >= R * E) return;
    int r = t / E;
    int e = t - r * E;
    int dst = eis[r * 2 * E + E + e];
    atomicAdd(&cnt[r * N + dst], 1);
}

// ---------------- dinv = rsqrt(cnt + 1) ----------------
__global__ void k_dinv(const int* __restrict__ cnt, float* __restrict__ dinv) {
    int t = blockIdx.x * blockDim.x + threadIdx.x;
    if (t < M) dinv[t] = rsqrtf((float)cnt[t] + 1.0f);
}

// ---------------- exclusive scan (3-kernel) ----------------
__global__ void k_scanA(const int* __restrict__ cnt, int* __restrict__ off,
                        int* __restrict__ blksum) {
    __shared__ int sh[BS];
    int t = blockIdx.x * BS + threadIdx.x;
    int v = (t < M) ? cnt[t] : 0;
    sh[threadIdx.x] = v;
    __syncthreads();
#pragma unroll
    for (int d = 1; d < BS; d <<= 1) {
        int x = (threadIdx.x >= d) ? sh[threadIdx.x - d] : 0;
        __syncthreads();
        sh[threadIdx.x] += x;
        __syncthreads();
    }
    int incl = sh[threadIdx.x];
    if (t < M) off[t] = incl - v;                 // exclusive
    if (threadIdx.x == BS - 1) blksum[blockIdx.x] = incl;
}

__global__ void k_scanB(int* __restrict__ blksum, int nb) {
    __shared__ int sh[BS];
    __shared__ int carry;
    if (threadIdx.x == 0) carry = 0;
    __syncthreads();
    for (int base = 0; base < nb; base += BS) {
        int t = base + threadIdx.x;
        int v = (t < nb) ? blksum[t] : 0;
        sh[threadIdx.x] = v;
        __syncthreads();
#pragma unroll
        for (int d = 1; d < BS; d <<= 1) {
            int x = (threadIdx.x >= d) ? sh[threadIdx.x - d] : 0;
            __syncthreads();
            sh[threadIdx.x] += x;
            __syncthreads();
        }
        int incl = sh[threadIdx.x];
        if (t < nb) blksum[t] = incl - v + carry;  // exclusive + carry
        __syncthreads();
        if (threadIdx.x == BS - 1) carry += incl;  // chunk total
        __syncthreads();
    }
}

__global__ void k_scanC(int* __restrict__ off, const int* __restrict__ blksum) {
    int t = blockIdx.x * BS + threadIdx.x;
    if (t < M) off[t] += blksum[blockIdx.x];
}

// ---------------- scatter src into CSR order (order within node irrelevant) ----
__global__ void k_scatter(const int* __restrict__ eis, int* __restrict__ cursor,
                          int* __restrict__ ssrc) {
    int t = blockIdx.x * blockDim.x + threadIdx.x;
    if (t >= R * E) return;
    int r = t / E;
    int e = t - r * E;
    int src = eis[r * 2 * E + e];
    int dst = eis[r * 2 * E + E + e];
    int pos = atomicAdd(&cursor[r * N + dst], 1);
    ssrc[pos] = src;      // global scan => relation r's segment starts at r*E
}

// ---------------- layer 1 fused: gather + relu + dot(wrow) -> g ----------------
// 32 lanes per (r, node). acc in registers; H0 row gathers are 128B coalesced.
__global__ void k_l1(const int* __restrict__ off, const int* __restrict__ cnt,
                     const int* __restrict__ ssrc, const float* __restrict__ dinv,
                     const float* __restrict__ H0, const float* __restrict__ b1,
                     const float* __restrict__ W2, float* __restrict__ g) {
    int t = blockIdx.x * blockDim.x + threadIdx.x;
    int j = t & 31;
    int ri = t >> 5;
    if (ri >= M) return;
    int i = ri % N;             // node within relation
    int rbase = ri - i;         // r*N
    float di = dinv[ri];
    float acc = di * H0[i * HID + j];          // self-loop term
    int base = off[ri];
    int end = base + cnt[ri];
    for (int k0 = base; k0 < end; k0 += 32) {
        int idx = k0 + j;
        int s = (idx < end) ? ssrc[idx] : 0;   // coalesced index load
        int m = min(32, end - k0);
        for (int jj = 0; jj < m; ++jj) {
            int sj = __shfl(s, jj, 32);
            acc = fmaf(dinv[rbase + sj], H0[sj * HID + j], acc);  // 128B coalesced
        }
    }
    float h = fmaxf(fmaf(di, acc, b1[j]), 0.f);
    float wr = 0.f;
#pragma unroll
    for (int k = 0; k < EMB; ++k) wr += W2[j * EMB + k];   // wrow[j], L1
    float p = h * wr;
#pragma unroll
    for (int o = 16; o > 0; o >>= 1) p += __shfl_xor(p, o, 32);
    if (j == 0) g[ri] = p;
}

// ---------------- layer 2 fused: scalar gather + finalize -> out ----------------
__global__ void k_l2(const int* __restrict__ off, const int* __restrict__ cnt,
                     const int* __restrict__ ssrc, const float* __restrict__ dinv,
                     const float* __restrict__ g, const float* __restrict__ b2,
                     float* __restrict__ out) {
    int t = blockIdx.x * blockDim.x + threadIdx.x;
    int j = t & 31;
    int ri = t >> 5;
    if (ri >= M) return;
    int i = ri % N;
    int rbase = ri - i;
    float di = dinv[ri];
    int base = off[ri];
    int end = base + cnt[ri];
    float val = 0.f;
    for (int idx = base + j; idx < end; idx += 32) {
        int s = ssrc[idx];
        val += dinv[rbase + s] * g[rbase + s];   // 4B gathers, L2-resident (1.6MB)
    }
#pragma unroll
    for (int o = 16; o > 0; o >>= 1) val += __shfl_xor(val, o, 32);
    if (j == 0) {
        float sb = 0.f;
#pragma unroll
        for (int k = 0; k < EMB; ++k) sb += b2[k];
        out[ri] = fmaf(di, val + di * g[ri], sb);
    }
}

extern "C" void kernel_launch(void* const* d_in, const int* in_sizes, int n_in,
                              void* d_out, int out_size, void* d_ws, size_t ws_size,
                              hipStream_t stream) {
    const float* x  = (const float*)d_in[0];
    const int*  eis = (const int*)d_in[1];
    const float* W1 = (const float*)d_in[2];
    const float* b1 = (const float*)d_in[3];
    const float* W2 = (const float*)d_in[4];
    const float* b2 = (const float*)d_in[5];
    float* out = (float*)d_out;

    // ws layout (4B units): H0 [N*32] | cnt [M] | off [M] | cursor [M] |
    //                       dinv [M] | g [M] | blksum [NB] | ssrc [R*E]
    // total ~= 44.8 MB (prev fused layout was 67.2 MB and ran, so it fits)
    float* H0     = (float*)d_ws;
    int*   cnt    = (int*)(H0 + (size_t)N * HID);
    int*   off    = cnt + M;
    int*   cursor = off + M;
    float* dinv   = (float*)(cursor + M);
    float* g      = dinv + M;
    int*   blksum = (int*)(g + M);
    int*   ssrc   = blksum + 2048;

    k_gemm_h0<<<(N * HID + BS - 1) / BS, BS, 0, stream>>>(x, W1, H0);

    hipMemsetAsync(cnt, 0, (size_t)M * sizeof(int), stream);
    k_count  <<<(R * E + BS - 1) / BS, BS, 0, stream>>>(eis, cnt);
    k_dinv   <<<(M + BS - 1) / BS, BS, 0, stream>>>(cnt, dinv);
    k_scanA  <<<NB, BS, 0, stream>>>(cnt, off, blksum);
    k_scanB  <<<1, BS, 0, stream>>>(blksum, NB);
    k_scanC  <<<NB, BS, 0, stream>>>(off, blksum);
    hipMemcpyAsync(cursor, off, (size_t)M * sizeof(int), hipMemcpyDeviceToDevice, stream);
    k_scatter<<<(R * E + BS - 1) / BS, BS, 0, stream>>>(eis, cursor, ssrc);
    k_l1     <<<(M * 32 + BS - 1) / BS, BS, 0, stream>>>(off, cnt, ssrc, dinv, H0, b1, W2, g);
    k_l2     <<<(M * 32 + BS - 1) / BS, BS, 0, stream>>>(off, cnt, ssrc, dinv, g, b2, out);
}